// Round 4
// baseline (653.365 us; speedup 1.0000x reference)
//
#include <hip/hip_runtime.h>
#include <hip/hip_bf16.h>
#include <cstdint>

// Problem constants
#define BB 32
#define SS 2048
#define QQ 1024
#define II 1024
#define AA 1024
#define MM (BB * SS)   // 65536 flattened rows

typedef __bf16 bf16x8 __attribute__((ext_vector_type(8)));
typedef float  f32x4  __attribute__((ext_vector_type(4)));

// Pack two fp32 -> two bf16 (round-half-away via +0x8000, then byte-perm).
__device__ __forceinline__ unsigned int pack_bf2(float a, float b) {
  unsigned ua = __builtin_bit_cast(unsigned, a) + 0x8000u;
  unsigned ub = __builtin_bit_cast(unsigned, b) + 0x8000u;
  return __builtin_amdgcn_perm(ub, ua, 0x07060302u);  // lo=bf16(a), hi=bf16(b)
}

// async global->LDS, 16B per lane. LDS dest = uniform base + lane*16.
__device__ __forceinline__ void gload_lds16(const void* g, void* l) {
  __builtin_amdgcn_global_load_lds(
      (const __attribute__((address_space(1))) void*)g,
      (__attribute__((address_space(3))) void*)l, 16, 0, 0);
}

// ---------------- U transpose+convert: Ut[n][k] = bf16(U[k][n]) ----------------
__global__ void __launch_bounds__(256) k_transpose_u(const float* __restrict__ U,
                                                     unsigned short* __restrict__ Ut) {
  __shared__ float t[64][65];
  const int n0 = blockIdx.x * 64, k0 = blockIdx.y * 64;
  const int c = threadIdx.x & 63, r0 = threadIdx.x >> 6;
#pragma unroll
  for (int r = r0; r < 64; r += 4) t[r][c] = U[(size_t)(k0 + r) * AA + n0 + c];
  __syncthreads();
#pragma unroll
  for (int r = r0; r < 64; r += 4) {
    __hip_bfloat16 h = __float2bfloat16(t[c][r]);
    Ut[(size_t)(n0 + r) * II + k0 + c] = __builtin_bit_cast(unsigned short, h);
  }
}

// ---------------- items fp32 -> bf16, PRE-SWIZZLED into MFMA A-fragment order ----
// Element (m,k) -> 16B slot ((m>>4)*32 + (k>>5))*64 + lane, lane = ((k>>3)&3)*16 + (m&15).
// LDS row stride padded 2048->2056B: phase-2 gather banks = (2m + 4*quadk + C) % 32
// -> 4-way on 8B reads = the b64 floor (was 16-way unpadded: 2048 % 128B == 0).
#define CRS 1028   // row stride in shorts (2056 B)
__global__ void __launch_bounds__(256) k_conv_swz(const float* __restrict__ in,
                                                  unsigned short* __restrict__ Aswz) {
  __shared__ unsigned short swz[16 * CRS];   // ~32.9 KB
  const int mt = blockIdx.x, tid = threadIdx.x;
  const float4* src = (const float4*)(in + (size_t)mt * 16 * 1024);
#pragma unroll
  for (int i = 0; i < 16; ++i) {
    const int e4 = i * 256 + tid;            // float4 index in strip
    const int m = e4 >> 8, q = e4 & 255;
    float4 f = src[e4];
    uint2 h;
    h.x = pack_bf2(f.x, f.y);
    h.y = pack_bf2(f.z, f.w);
    *(uint2*)&swz[m * CRS + q * 4] = h;
  }
  __syncthreads();
  uint4* dst = (uint4*)Aswz + (size_t)mt * 2048;   // 2048 slots per strip
#pragma unroll
  for (int i = 0; i < 8; ++i) {
    const int s = i * 256 + tid;             // slot index in strip
    const int m = s & 15;
    const int quadk = (s & 63) >> 4;
    const int kc = s >> 6;
    const int idx = m * CRS + kc * 32 + quadk * 8;
    uint2 lo = *(const uint2*)&swz[idx];
    uint2 hi = *(const uint2*)&swz[idx + 4];
    uint4 w; w.x = lo.x; w.y = lo.y; w.z = hi.x; w.w = hi.y;
    dst[s] = w;
  }
}

// ---------------- pq[b][a] = sum_q queries[b][q] * W[q][a] (W read exactly once) ----
__global__ void __launch_bounds__(256) k_pq(const float* __restrict__ q,
                                            const float* __restrict__ W,
                                            float* __restrict__ pq) {
  __shared__ float qs[32 * 256];
  const int ab = blockIdx.x, qc = blockIdx.y, tid = threadIdx.x;
#pragma unroll
  for (int j = 0; j < 32; ++j) qs[j * 256 + tid] = q[j * QQ + qc * 256 + tid];
  __syncthreads();
  const int a  = ab * 128 + (tid & 127);
  const int bg = tid >> 7;
  float acc[16] = {};
  const float* Wp = W + (size_t)(qc * 256) * AA + a;
  for (int i = 0; i < 256; ++i) {
    const float w = Wp[(size_t)i * AA];
#pragma unroll
    for (int bb = 0; bb < 16; ++bb) acc[bb] += w * qs[(bg * 16 + bb) * 256 + i];
  }
#pragma unroll
  for (int bb = 0; bb < 16; ++bb) atomicAdd(&pq[(bg * 16 + bb) * AA + a], acc[bb]);
}

// Shared epilogue: x=acc+pq; tanh; *v; 16-col butterfly reduce; atomic into react.
__device__ __forceinline__ void react_epilogue(f32x4 (&acc)[4][4], const float* pq,
                                               const float* v, float* react,
                                               int b, int m0, int n0, int wm, int wn,
                                               int quad, int sx) {
  float pqv[4], vv[4];
#pragma unroll
  for (int ni = 0; ni < 4; ++ni) {
    const int n = n0 + wn * 64 + ni * 16 + sx;
    pqv[ni] = pq[b * AA + n];
    vv[ni]  = v[n];
  }
#pragma unroll
  for (int mi = 0; mi < 4; ++mi) {
#pragma unroll
    for (int reg = 0; reg < 4; ++reg) {
      float ssum = 0.f;
#pragma unroll
      for (int ni = 0; ni < 4; ++ni) {
        const float x = acc[mi][ni][reg] + pqv[ni];
        const float e = __expf(2.f * x);
        const float t = 1.f - 2.f * __builtin_amdgcn_rcpf(e + 1.f);  // tanh(x)
        ssum += t * vv[ni];
      }
      ssum += __shfl_xor(ssum, 1);
      ssum += __shfl_xor(ssum, 2);
      ssum += __shfl_xor(ssum, 4);
      ssum += __shfl_xor(ssum, 8);
      if (sx == 0) {
        const int m = m0 + wm * 64 + mi * 16 + quad * 4 + reg;
        atomicAdd(&react[m], ssum);
      }
    }
  }
}

// ---------------- PATH A: software-pipelined. A-frags prefetched to regs, B dbuf LDS ----
// Per iter: issue next B (global_load_lds) + next A (dwordx4) BEFORE this iter's
// 8 ds_read + 32 MFMA -> the barrier's vmcnt(0) drain is hidden behind compute.
__global__ void __launch_bounds__(256, 3) k_gemm_bf(const unsigned short* __restrict__ Aswz,
                                                    const unsigned short* __restrict__ Ut,
                                                    const float* __restrict__ pq,
                                                    const float* __restrict__ v,
                                                    float* __restrict__ react) {
  __shared__ unsigned short Bs0[128 * 64];   // 16KB
  __shared__ unsigned short Bs1[128 * 64];   // 16KB

  const int tid  = threadIdx.x;
  const int lane = tid & 63, wid = tid >> 6;
  const int wm = wid >> 1, wn = wid & 1;
  const int quad = lane >> 4, sx = lane & 15;

  const unsigned id = blockIdx.x;
  const int xcd = id & 7;
  const int j   = id >> 3;
  const int mtile = xcd + 8 * (j >> 3);
  const int ntile = j & 7;
  const int m0 = mtile * 128, n0 = ntile * 128;
  const int b  = m0 >> 11;

  // B staging map (global-side swizzle; LDS stays lane-contiguous for global_load_lds)
  const int r_loc = lane >> 3;
  const int cch   = lane & 7;
  const int gch   = cch ^ r_loc;

  const bf16x8* Ab = (const bf16x8*)Aswz;
  const int m16b = (m0 + wm * 64) >> 4;

  f32x4 acc[4][4] = {};
  bf16x8 afA[2][4], afB[2][4];

#define ISSUE_B(BUF, KK)                                                        \
  {                                                                             \
    const int _k0 = (KK) * 64;                                                  \
    _Pragma("unroll")                                                           \
    for (int jj = 0; jj < 4; ++jj) {                                            \
      const int rB = wid * 32 + jj * 8 + r_loc;                                 \
      gload_lds16(Ut + (size_t)(n0 + rB) * II + _k0 + gch * 8,                  \
                  &BUF[(wid * 32 + jj * 8) * 64]);                              \
    }                                                                           \
  }

#define LOAD_A(AF, KK)                                                          \
  {                                                                             \
    _Pragma("unroll")                                                           \
    for (int ks = 0; ks < 2; ++ks) {                                            \
      const int g = (KK) * 2 + ks;                                              \
      _Pragma("unroll")                                                         \
      for (int mi = 0; mi < 4; ++mi)                                            \
        AF[ks][mi] = Ab[(size_t)((m16b + mi) * 32 + g) * 64 + lane];            \
    }                                                                           \
  }

#define GEMM_STEP(BUF, AF)                                                      \
  {                                                                             \
    _Pragma("unroll")                                                           \
    for (int ks = 0; ks < 2; ++ks) {                                            \
      bf16x8 bfv[4];                                                            \
      _Pragma("unroll")                                                         \
      for (int ni = 0; ni < 4; ++ni) {                                          \
        const int r = wn * 64 + ni * 16 + sx;                                   \
        const int c = (ks * 4 + quad) ^ (r & 7);                                \
        bfv[ni] = *(const bf16x8*)&BUF[r * 64 + c * 8];                         \
      }                                                                         \
      _Pragma("unroll")                                                         \
      for (int mi = 0; mi < 4; ++mi)                                            \
        _Pragma("unroll")                                                       \
        for (int ni = 0; ni < 4; ++ni)                                          \
          acc[mi][ni] = __builtin_amdgcn_mfma_f32_16x16x32_bf16(                \
              AF[ks][mi], bfv[ni], acc[mi][ni], 0, 0, 0);                       \
    }                                                                           \
  }

  // prologue
  ISSUE_B(Bs0, 0);
  LOAD_A(afA, 0);
  __syncthreads();   // vmcnt drain: B(0) in LDS, afA ready

  for (int kk = 0; kk < 16; kk += 2) {
    // iter kk: compute Bs0/afA, prefetch kk+1 -> Bs1/afB  (kk+1 <= 15 always)
    ISSUE_B(Bs1, kk + 1);
    LOAD_A(afB, kk + 1);
    GEMM_STEP(Bs0, afA);
    __syncthreads();   // drain hidden behind the 32 MFMA above
    // iter kk+1: compute Bs1/afB, prefetch kk+2 -> Bs0/afA
    if (kk + 2 < 16) {
      ISSUE_B(Bs0, kk + 2);
      LOAD_A(afA, kk + 2);
    }
    GEMM_STEP(Bs1, afB);
    __syncthreads();
  }

  react_epilogue(acc, pq, v, react, b, m0, n0, wm, wn, quad, sx);
#undef ISSUE_B
#undef LOAD_A
#undef GEMM_STEP
}

// ---------------- PATH B (fallback, ws too small): in-kernel fp32->bf16 staging ----
__global__ void __launch_bounds__(256) k_gemm_f32(const float* __restrict__ items,
                                                  const unsigned short* __restrict__ Ut,
                                                  const float* __restrict__ pq,
                                                  const float* __restrict__ v,
                                                  float* __restrict__ react) {
  __shared__ unsigned short As[128 * 64];
  __shared__ unsigned short Bs[128 * 64];
  const int tid  = threadIdx.x;
  const int lane = tid & 63, wid = tid >> 6;
  const int wm = wid >> 1, wn = wid & 1;
  const int quad = lane >> 4, sx = lane & 15;
  const unsigned id = blockIdx.x;
  const int xcd = id & 7;
  const int j   = id >> 3;
  const int mtile = xcd + 8 * (j >> 3);
  const int ntile = j & 7;
  const int m0 = mtile * 128, n0 = ntile * 128;
  const int b  = m0 >> 11;
  const int ar = tid >> 2, aq = tid & 3;
  const int bn = tid >> 1, bh = tid & 1;
  f32x4 acc[4][4] = {};
  for (int kk = 0; kk < 16; ++kk) {
    const int k0 = kk * 64;
    __syncthreads();
#pragma unroll
    for (int rr = 0; rr < 2; ++rr) {
      const int r = ar + rr * 64;
      const float* g = items + (size_t)(m0 + r) * II + k0 + aq * 16;
      float4 f0 = ((const float4*)g)[0];
      float4 f1 = ((const float4*)g)[1];
      float4 f2 = ((const float4*)g)[2];
      float4 f3 = ((const float4*)g)[3];
      uint4 w0, w1;
      w0.x = pack_bf2(f0.x, f0.y); w0.y = pack_bf2(f0.z, f0.w);
      w0.z = pack_bf2(f1.x, f1.y); w0.w = pack_bf2(f1.z, f1.w);
      w1.x = pack_bf2(f2.x, f2.y); w1.y = pack_bf2(f2.z, f2.w);
      w1.z = pack_bf2(f3.x, f3.y); w1.w = pack_bf2(f3.z, f3.w);
      const int c0 = (2 * aq) ^ (r & 7);
      const int c1 = (2 * aq + 1) ^ (r & 7);
      *(uint4*)&As[r * 64 + c0 * 8] = w0;
      *(uint4*)&As[r * 64 + c1 * 8] = w1;
    }
    {
      const unsigned short* g = Ut + (size_t)(n0 + bn) * II + k0 + bh * 32;
#pragma unroll
      for (int jj = 0; jj < 4; ++jj) {
        uint4 w = ((const uint4*)g)[jj];
        const int c = (bh * 4 + jj) ^ (bn & 7);
        *(uint4*)&Bs[bn * 64 + c * 8] = w;
      }
    }
    __syncthreads();
#pragma unroll
    for (int ks = 0; ks < 2; ++ks) {
      bf16x8 af[4], bfv[4];
#pragma unroll
      for (int mi = 0; mi < 4; ++mi) {
        const int r = wm * 64 + mi * 16 + sx;
        const int c = (ks * 4 + quad) ^ (r & 7);
        af[mi] = *(const bf16x8*)&As[r * 64 + c * 8];
      }
#pragma unroll
      for (int ni = 0; ni < 4; ++ni) {
        const int r = wn * 64 + ni * 16 + sx;
        const int c = (ks * 4 + quad) ^ (r & 7);
        bfv[ni] = *(const bf16x8*)&Bs[r * 64 + c * 8];
      }
#pragma unroll
      for (int mi = 0; mi < 4; ++mi)
#pragma unroll
        for (int ni = 0; ni < 4; ++ni)
          acc[mi][ni] = __builtin_amdgcn_mfma_f32_16x16x32_bf16(af[mi], bfv[ni], acc[mi][ni], 0, 0, 0);
    }
  }
  react_epilogue(acc, pq, v, react, b, m0, n0, wm, wn, quad, sx);
}

// ---------------- masked softmax over S per batch ----------------
__global__ void __launch_bounds__(256) k_softmax(const float* __restrict__ react,
                                                 const int* __restrict__ weights,
                                                 float* __restrict__ scores) {
  const int b = blockIdx.x, tid = threadIdx.x;
  const int lane = tid & 63, wid = tid >> 6;
  __shared__ float redm[4], reds[4];
  float vals[8];
  float mx = -3.0e38f;
#pragma unroll
  for (int j = 0; j < 8; ++j) {
    const int s = j * 256 + tid;
    const float r = react[b * SS + s];
    const int w = weights[b * SS + s];
    const float val = (w != 0) ? r : -3.0e38f;
    vals[j] = val;
    mx = fmaxf(mx, val);
  }
#pragma unroll
  for (int off = 1; off < 64; off <<= 1) mx = fmaxf(mx, __shfl_xor(mx, off));
  if (lane == 0) redm[wid] = mx;
  __syncthreads();
  mx = fmaxf(fmaxf(redm[0], redm[1]), fmaxf(redm[2], redm[3]));
  float e[8], sum = 0.f;
#pragma unroll
  for (int j = 0; j < 8; ++j) {
    e[j] = (vals[j] < -1.0e38f) ? 0.f : __expf(vals[j] - mx);
    sum += e[j];
  }
#pragma unroll
  for (int off = 1; off < 64; off <<= 1) sum += __shfl_xor(sum, off);
  if (lane == 0) reds[wid] = sum;
  __syncthreads();
  const float inv = 1.f / (reds[0] + reds[1] + reds[2] + reds[3]);
#pragma unroll
  for (int j = 0; j < 8; ++j) scores[b * SS + j * 256 + tid] = e[j] * inv;
}

// ---------------- blended: block-local compaction + branch-free x4 loop ----------------
__global__ void __launch_bounds__(256) k_blended(const float* __restrict__ items,
                                                 const float* __restrict__ scores,
                                                 float* __restrict__ out) {
  const int b = blockIdx.x, chunk = blockIdx.y, tid = threadIdx.x;
  __shared__ int   lidx[132];
  __shared__ float lsc[132];
  __shared__ int   lcount;
  if (tid == 0) lcount = 0;
  __syncthreads();
  if (tid < 128) {
    const int s = chunk * 128 + tid;
    const float sc = scores[b * SS + s];
    if (sc != 0.f) {
      const int p = atomicAdd(&lcount, 1);
      lidx[p] = s; lsc[p] = sc;
    }
  }
  __syncthreads();
  const int cnt = lcount;
  if (tid < 4) {
    const int p = cnt + tid;
    if (p < 132) { lidx[p] = chunk * 128; lsc[p] = 0.f; }
  }
  __syncthreads();
  const int cnt4 = (cnt + 3) & ~3;
  const float4* base = (const float4*)(items + (size_t)b * SS * II);
  float4 acc = {0.f, 0.f, 0.f, 0.f};
  for (int j0 = 0; j0 < cnt4; j0 += 4) {
    const int   s0 = lidx[j0],   s1 = lidx[j0+1], s2 = lidx[j0+2], s3 = lidx[j0+3];
    const float w0 = lsc[j0],    w1 = lsc[j0+1],  w2 = lsc[j0+2],  w3 = lsc[j0+3];
    const float4 x0 = base[(size_t)s0 * 256 + tid];
    const float4 x1 = base[(size_t)s1 * 256 + tid];
    const float4 x2 = base[(size_t)s2 * 256 + tid];
    const float4 x3 = base[(size_t)s3 * 256 + tid];
    acc.x += w0*x0.x + w1*x1.x + w2*x2.x + w3*x3.x;
    acc.y += w0*x0.y + w1*x1.y + w2*x2.y + w3*x3.y;
    acc.z += w0*x0.z + w1*x1.z + w2*x2.z + w3*x3.z;
    acc.w += w0*x0.w + w1*x1.w + w2*x2.w + w3*x3.w;
  }
  float* o = out + b * II + tid * 4;
  atomicAdd(o + 0, acc.x);
  atomicAdd(o + 1, acc.y);
  atomicAdd(o + 2, acc.z);
  atomicAdd(o + 3, acc.w);
}

extern "C" void kernel_launch(void* const* d_in, const int* in_sizes, int n_in,
                              void* d_out, int out_size, void* d_ws, size_t ws_size,
                              hipStream_t stream) {
  const float* queries = (const float*)d_in[0];
  const float* items   = (const float*)d_in[1];
  const int*   weights = (const int*)d_in[2];
  const float* W       = (const float*)d_in[3];
  const float* U       = (const float*)d_in[4];
  const float* v       = (const float*)d_in[5];
  float* out = (float*)d_out;

  char* ws = (char*)d_ws;
  unsigned short* Ut = (unsigned short*)ws;                         // 2 MB
  float* pq    = (float*)(ws + (2u << 20));                         // 128 KB
  float* react = (float*)(ws + (2u << 20) + (128u << 10));          // 256 KB
  const size_t bf_off = (2u << 20) + (128u << 10) + (256u << 10);
  unsigned short* Aswz = (unsigned short*)(ws + bf_off);            // 128 MB (path A)
  const bool pathA = ws_size >= bf_off + (size_t)MM * II * 2;

  hipMemsetAsync(pq, 0, BB * AA * sizeof(float), stream);
  hipMemsetAsync(react, 0, MM * sizeof(float), stream);
  hipMemsetAsync(out, 0, BB * II * sizeof(float), stream);

  k_transpose_u<<<dim3(16, 16), 256, 0, stream>>>(U, Ut);
  k_pq<<<dim3(8, 4), 256, 0, stream>>>(queries, W, pq);
  if (pathA) {
    k_conv_swz<<<dim3(4096), 256, 0, stream>>>(items, Aswz);
    k_gemm_bf<<<dim3(4096), 256, 0, stream>>>(Aswz, Ut, pq, v, react);
  } else {
    k_gemm_f32<<<dim3(4096), 256, 0, stream>>>(items, Ut, pq, v, react);
  }
  k_softmax<<<dim3(BB), 256, 0, stream>>>(react, weights, out + BB * II);
  k_blended<<<dim3(BB, 16), 256, 0, stream>>>(items, out + BB * II, out);
}

// Round 5
// 633.386 us; speedup vs baseline: 1.0315x; 1.0315x over previous
//
#include <hip/hip_runtime.h>
#include <hip/hip_bf16.h>
#include <cstdint>

// Problem constants
#define BB 32
#define SS 2048
#define QQ 1024
#define II 1024
#define AA 1024
#define MM (BB * SS)   // 65536 flattened rows

typedef __bf16 bf16x8 __attribute__((ext_vector_type(8)));
typedef float  f32x4  __attribute__((ext_vector_type(4)));

// Pack two fp32 -> two bf16 (round-half-away via +0x8000, then byte-perm).
__device__ __forceinline__ unsigned int pack_bf2(float a, float b) {
  unsigned ua = __builtin_bit_cast(unsigned, a) + 0x8000u;
  unsigned ub = __builtin_bit_cast(unsigned, b) + 0x8000u;
  return __builtin_amdgcn_perm(ub, ua, 0x07060302u);  // lo=bf16(a), hi=bf16(b)
}

// async global->LDS, 16B per lane. LDS dest = uniform base + lane*16.
__device__ __forceinline__ void gload_lds16(const void* g, void* l) {
  __builtin_amdgcn_global_load_lds(
      (const __attribute__((address_space(1))) void*)g,
      (__attribute__((address_space(3))) void*)l, 16, 0, 0);
}

// ---------------- U transpose+convert: Ut[n][k] = bf16(U[k][n]) ----------------
__global__ void __launch_bounds__(256) k_transpose_u(const float* __restrict__ U,
                                                     unsigned short* __restrict__ Ut) {
  __shared__ float t[64][65];
  const int n0 = blockIdx.x * 64, k0 = blockIdx.y * 64;
  const int c = threadIdx.x & 63, r0 = threadIdx.x >> 6;
#pragma unroll
  for (int r = r0; r < 64; r += 4) t[r][c] = U[(size_t)(k0 + r) * AA + n0 + c];
  __syncthreads();
#pragma unroll
  for (int r = r0; r < 64; r += 4) {
    __hip_bfloat16 h = __float2bfloat16(t[c][r]);
    Ut[(size_t)(n0 + r) * II + k0 + c] = __builtin_bit_cast(unsigned short, h);
  }
}

// ---------------- items fp32 -> bf16, PRE-SWIZZLED into MFMA A-fragment order ----
// Element (m,k) -> 16B slot ((m>>4)*32 + (k>>5))*64 + lane, lane = ((k>>3)&3)*16 + (m&15).
// LDS row stride padded 2048->2056B so phase-2 gathers avoid the 16-way wrap conflict.
#define CRS 1028   // row stride in shorts (2056 B)
__global__ void __launch_bounds__(256) k_conv_swz(const float* __restrict__ in,
                                                  unsigned short* __restrict__ Aswz) {
  __shared__ unsigned short swz[16 * CRS];   // ~32.9 KB
  const int mt = blockIdx.x, tid = threadIdx.x;
  const float4* src = (const float4*)(in + (size_t)mt * 16 * 1024);
#pragma unroll
  for (int i = 0; i < 16; ++i) {
    const int e4 = i * 256 + tid;            // float4 index in strip
    const int m = e4 >> 8, q = e4 & 255;
    float4 f = src[e4];
    uint2 h;
    h.x = pack_bf2(f.x, f.y);
    h.y = pack_bf2(f.z, f.w);
    *(uint2*)&swz[m * CRS + q * 4] = h;
  }
  __syncthreads();
  uint4* dst = (uint4*)Aswz + (size_t)mt * 2048;   // 2048 slots per strip
#pragma unroll
  for (int i = 0; i < 8; ++i) {
    const int s = i * 256 + tid;             // slot index in strip
    const int m = s & 15;
    const int quadk = (s & 63) >> 4;
    const int kc = s >> 6;
    const int idx = m * CRS + kc * 32 + quadk * 8;
    uint2 lo = *(const uint2*)&swz[idx];
    uint2 hi = *(const uint2*)&swz[idx + 4];
    uint4 w; w.x = lo.x; w.y = lo.y; w.z = hi.x; w.w = hi.y;
    dst[s] = w;
  }
}

// ---------------- pq[b][a] = sum_q queries[b][q] * W[q][a] (W read exactly once) ----
__global__ void __launch_bounds__(256) k_pq(const float* __restrict__ q,
                                            const float* __restrict__ W,
                                            float* __restrict__ pq) {
  __shared__ float qs[32 * 256];
  const int ab = blockIdx.x, qc = blockIdx.y, tid = threadIdx.x;
#pragma unroll
  for (int j = 0; j < 32; ++j) qs[j * 256 + tid] = q[j * QQ + qc * 256 + tid];
  __syncthreads();
  const int a  = ab * 128 + (tid & 127);
  const int bg = tid >> 7;
  float acc[16] = {};
  const float* Wp = W + (size_t)(qc * 256) * AA + a;
  for (int i = 0; i < 256; ++i) {
    const float w = Wp[(size_t)i * AA];
#pragma unroll
    for (int bb = 0; bb < 16; ++bb) acc[bb] += w * qs[(bg * 16 + bb) * 256 + i];
  }
#pragma unroll
  for (int bb = 0; bb < 16; ++bb) atomicAdd(&pq[(bg * 16 + bb) * AA + a], acc[bb]);
}

// Shared epilogue: x=acc+pq; tanh; *v; 16-col butterfly reduce; atomic into react.
__device__ __forceinline__ void react_epilogue(f32x4 (&acc)[4][4], const float* pq,
                                               const float* v, float* react,
                                               int b, int m0, int n0, int wm, int wn,
                                               int quad, int sx) {
  float pqv[4], vv[4];
#pragma unroll
  for (int ni = 0; ni < 4; ++ni) {
    const int n = n0 + wn * 64 + ni * 16 + sx;
    pqv[ni] = pq[b * AA + n];
    vv[ni]  = v[n];
  }
#pragma unroll
  for (int mi = 0; mi < 4; ++mi) {
#pragma unroll
    for (int reg = 0; reg < 4; ++reg) {
      float ssum = 0.f;
#pragma unroll
      for (int ni = 0; ni < 4; ++ni) {
        const float x = acc[mi][ni][reg] + pqv[ni];
        const float e = __expf(2.f * x);
        const float t = 1.f - 2.f * __builtin_amdgcn_rcpf(e + 1.f);  // tanh(x)
        ssum += t * vv[ni];
      }
      ssum += __shfl_xor(ssum, 1);
      ssum += __shfl_xor(ssum, 2);
      ssum += __shfl_xor(ssum, 4);
      ssum += __shfl_xor(ssum, 8);
      if (sx == 0) {
        const int m = m0 + wm * 64 + mi * 16 + quad * 4 + reg;
        atomicAdd(&react[m], ssum);
      }
    }
  }
}

// ---------------- PATH A: B double-buffered in LDS; A loaded in-iter to ONE reg set ----
// Register budget at 3 blk/CU (512/3 ~ 170/wave): acc 64 AGPR + af 32 + bfv 16 + addr
// ~ 145 total -> no spill (R4's afA+afB variant needed ~190 -> spilled, WRITE_SIZE 3.5x).
// Per half-iter: LOAD_A first (oldest in vmcnt queue -> pre-MFMA wait leaves B's
// global_load_lds in flight), then ISSUE_B(next buf), then GEMM on current buf;
// the barrier's vmcnt(0) drain of next-B is covered by the 32 MFMAs above it.
__global__ void __launch_bounds__(256, 3) k_gemm_bf(const unsigned short* __restrict__ Aswz,
                                                    const unsigned short* __restrict__ Ut,
                                                    const float* __restrict__ pq,
                                                    const float* __restrict__ v,
                                                    float* __restrict__ react) {
  __shared__ unsigned short Bs0[128 * 64];   // 16KB
  __shared__ unsigned short Bs1[128 * 64];   // 16KB

  const int tid  = threadIdx.x;
  const int lane = tid & 63, wid = tid >> 6;
  const int wm = wid >> 1, wn = wid & 1;
  const int quad = lane >> 4, sx = lane & 15;

  const unsigned id = blockIdx.x;
  const int xcd = id & 7;
  const int j   = id >> 3;
  const int mtile = xcd + 8 * (j >> 3);
  const int ntile = j & 7;
  const int m0 = mtile * 128, n0 = ntile * 128;
  const int b  = m0 >> 11;

  // B staging map (global-side swizzle; LDS stays lane-contiguous for global_load_lds)
  const int r_loc = lane >> 3;
  const int cch   = lane & 7;
  const int gch   = cch ^ r_loc;

  const bf16x8* Ab = (const bf16x8*)Aswz;
  const int m16b = (m0 + wm * 64) >> 4;

  f32x4 acc[4][4] = {};
  bf16x8 af[2][4];

#define ISSUE_B(BUF, KK)                                                        \
  {                                                                             \
    const int _k0 = (KK) * 64;                                                  \
    _Pragma("unroll")                                                           \
    for (int jj = 0; jj < 4; ++jj) {                                            \
      const int rB = wid * 32 + jj * 8 + r_loc;                                 \
      gload_lds16(Ut + (size_t)(n0 + rB) * II + _k0 + gch * 8,                  \
                  &BUF[(wid * 32 + jj * 8) * 64]);                              \
    }                                                                           \
  }

#define LOAD_A(KK)                                                              \
  {                                                                             \
    _Pragma("unroll")                                                           \
    for (int ks = 0; ks < 2; ++ks) {                                            \
      const int g = (KK) * 2 + ks;                                              \
      _Pragma("unroll")                                                         \
      for (int mi = 0; mi < 4; ++mi)                                            \
        af[ks][mi] = Ab[(size_t)((m16b + mi) * 32 + g) * 64 + lane];            \
    }                                                                           \
  }

#define GEMM_STEP(BUF)                                                          \
  {                                                                             \
    _Pragma("unroll")                                                           \
    for (int ks = 0; ks < 2; ++ks) {                                            \
      bf16x8 bfv[4];                                                            \
      _Pragma("unroll")                                                         \
      for (int ni = 0; ni < 4; ++ni) {                                          \
        const int r = wn * 64 + ni * 16 + sx;                                   \
        const int c = (ks * 4 + quad) ^ (r & 7);                                \
        bfv[ni] = *(const bf16x8*)&BUF[r * 64 + c * 8];                         \
      }                                                                         \
      _Pragma("unroll")                                                         \
      for (int mi = 0; mi < 4; ++mi)                                            \
        _Pragma("unroll")                                                       \
        for (int ni = 0; ni < 4; ++ni)                                          \
          acc[mi][ni] = __builtin_amdgcn_mfma_f32_16x16x32_bf16(                \
              af[ks][mi], bfv[ni], acc[mi][ni], 0, 0, 0);                       \
    }                                                                           \
  }

  // prologue: B(0) resident before loop
  ISSUE_B(Bs0, 0);
  __syncthreads();

  for (int kk = 0; kk < 16; kk += 2) {
    // half-iter kk: A(kk) -> regs (oldest), prefetch B(kk+1) -> Bs1, compute on Bs0
    LOAD_A(kk);
    ISSUE_B(Bs1, kk + 1);
    GEMM_STEP(Bs0);
    __syncthreads();                 // drains B(kk+1); hidden behind the MFMAs above
    // half-iter kk+1: A(kk+1) -> regs, prefetch B(kk+2) -> Bs0, compute on Bs1
    LOAD_A(kk + 1);
    if (kk + 2 < 16) ISSUE_B(Bs0, kk + 2);
    GEMM_STEP(Bs1);
    __syncthreads();
  }

  react_epilogue(acc, pq, v, react, b, m0, n0, wm, wn, quad, sx);
#undef ISSUE_B
#undef LOAD_A
#undef GEMM_STEP
}

// ---------------- PATH B (fallback, ws too small): in-kernel fp32->bf16 staging ----
__global__ void __launch_bounds__(256) k_gemm_f32(const float* __restrict__ items,
                                                  const unsigned short* __restrict__ Ut,
                                                  const float* __restrict__ pq,
                                                  const float* __restrict__ v,
                                                  float* __restrict__ react) {
  __shared__ unsigned short As[128 * 64];
  __shared__ unsigned short Bs[128 * 64];
  const int tid  = threadIdx.x;
  const int lane = tid & 63, wid = tid >> 6;
  const int wm = wid >> 1, wn = wid & 1;
  const int quad = lane >> 4, sx = lane & 15;
  const unsigned id = blockIdx.x;
  const int xcd = id & 7;
  const int j   = id >> 3;
  const int mtile = xcd + 8 * (j >> 3);
  const int ntile = j & 7;
  const int m0 = mtile * 128, n0 = ntile * 128;
  const int b  = m0 >> 11;
  const int ar = tid >> 2, aq = tid & 3;
  const int bn = tid >> 1, bh = tid & 1;
  f32x4 acc[4][4] = {};
  for (int kk = 0; kk < 16; ++kk) {
    const int k0 = kk * 64;
    __syncthreads();
#pragma unroll
    for (int rr = 0; rr < 2; ++rr) {
      const int r = ar + rr * 64;
      const float* g = items + (size_t)(m0 + r) * II + k0 + aq * 16;
      float4 f0 = ((const float4*)g)[0];
      float4 f1 = ((const float4*)g)[1];
      float4 f2 = ((const float4*)g)[2];
      float4 f3 = ((const float4*)g)[3];
      uint4 w0, w1;
      w0.x = pack_bf2(f0.x, f0.y); w0.y = pack_bf2(f0.z, f0.w);
      w0.z = pack_bf2(f1.x, f1.y); w0.w = pack_bf2(f1.z, f1.w);
      w1.x = pack_bf2(f2.x, f2.y); w1.y = pack_bf2(f2.z, f2.w);
      w1.z = pack_bf2(f3.x, f3.y); w1.w = pack_bf2(f3.z, f3.w);
      const int c0 = (2 * aq) ^ (r & 7);
      const int c1 = (2 * aq + 1) ^ (r & 7);
      *(uint4*)&As[r * 64 + c0 * 8] = w0;
      *(uint4*)&As[r * 64 + c1 * 8] = w1;
    }
    {
      const unsigned short* g = Ut + (size_t)(n0 + bn) * II + k0 + bh * 32;
#pragma unroll
      for (int jj = 0; jj < 4; ++jj) {
        uint4 w = ((const uint4*)g)[jj];
        const int c = (bh * 4 + jj) ^ (bn & 7);
        *(uint4*)&Bs[bn * 64 + c * 8] = w;
      }
    }
    __syncthreads();
#pragma unroll
    for (int ks = 0; ks < 2; ++ks) {
      bf16x8 af[4], bfv[4];
#pragma unroll
      for (int mi = 0; mi < 4; ++mi) {
        const int r = wm * 64 + mi * 16 + sx;
        const int c = (ks * 4 + quad) ^ (r & 7);
        af[mi] = *(const bf16x8*)&As[r * 64 + c * 8];
      }
#pragma unroll
      for (int ni = 0; ni < 4; ++ni) {
        const int r = wn * 64 + ni * 16 + sx;
        const int c = (ks * 4 + quad) ^ (r & 7);
        bfv[ni] = *(const bf16x8*)&Bs[r * 64 + c * 8];
      }
#pragma unroll
      for (int mi = 0; mi < 4; ++mi)
#pragma unroll
        for (int ni = 0; ni < 4; ++ni)
          acc[mi][ni] = __builtin_amdgcn_mfma_f32_16x16x32_bf16(af[mi], bfv[ni], acc[mi][ni], 0, 0, 0);
    }
  }
  react_epilogue(acc, pq, v, react, b, m0, n0, wm, wn, quad, sx);
}

// ---------------- masked softmax over S per batch ----------------
__global__ void __launch_bounds__(256) k_softmax(const float* __restrict__ react,
                                                 const int* __restrict__ weights,
                                                 float* __restrict__ scores) {
  const int b = blockIdx.x, tid = threadIdx.x;
  const int lane = tid & 63, wid = tid >> 6;
  __shared__ float redm[4], reds[4];
  float vals[8];
  float mx = -3.0e38f;
#pragma unroll
  for (int j = 0; j < 8; ++j) {
    const int s = j * 256 + tid;
    const float r = react[b * SS + s];
    const int w = weights[b * SS + s];
    const float val = (w != 0) ? r : -3.0e38f;
    vals[j] = val;
    mx = fmaxf(mx, val);
  }
#pragma unroll
  for (int off = 1; off < 64; off <<= 1) mx = fmaxf(mx, __shfl_xor(mx, off));
  if (lane == 0) redm[wid] = mx;
  __syncthreads();
  mx = fmaxf(fmaxf(redm[0], redm[1]), fmaxf(redm[2], redm[3]));
  float e[8], sum = 0.f;
#pragma unroll
  for (int j = 0; j < 8; ++j) {
    e[j] = (vals[j] < -1.0e38f) ? 0.f : __expf(vals[j] - mx);
    sum += e[j];
  }
#pragma unroll
  for (int off = 1; off < 64; off <<= 1) sum += __shfl_xor(sum, off);
  if (lane == 0) reds[wid] = sum;
  __syncthreads();
  const float inv = 1.f / (reds[0] + reds[1] + reds[2] + reds[3]);
#pragma unroll
  for (int j = 0; j < 8; ++j) scores[b * SS + j * 256 + tid] = e[j] * inv;
}

// ---------------- blended: block-local compaction + branch-free x4 loop ----------------
__global__ void __launch_bounds__(256) k_blended(const float* __restrict__ items,
                                                 const float* __restrict__ scores,
                                                 float* __restrict__ out) {
  const int b = blockIdx.x, chunk = blockIdx.y, tid = threadIdx.x;
  __shared__ int   lidx[132];
  __shared__ float lsc[132];
  __shared__ int   lcount;
  if (tid == 0) lcount = 0;
  __syncthreads();
  if (tid < 128) {
    const int s = chunk * 128 + tid;
    const float sc = scores[b * SS + s];
    if (sc != 0.f) {
      const int p = atomicAdd(&lcount, 1);
      lidx[p] = s; lsc[p] = sc;
    }
  }
  __syncthreads();
  const int cnt = lcount;
  if (tid < 4) {
    const int p = cnt + tid;
    if (p < 132) { lidx[p] = chunk * 128; lsc[p] = 0.f; }
  }
  __syncthreads();
  const int cnt4 = (cnt + 3) & ~3;
  const float4* base = (const float4*)(items + (size_t)b * SS * II);
  float4 acc = {0.f, 0.f, 0.f, 0.f};
  for (int j0 = 0; j0 < cnt4; j0 += 4) {
    const int   s0 = lidx[j0],   s1 = lidx[j0+1], s2 = lidx[j0+2], s3 = lidx[j0+3];
    const float w0 = lsc[j0],    w1 = lsc[j0+1],  w2 = lsc[j0+2],  w3 = lsc[j0+3];
    const float4 x0 = base[(size_t)s0 * 256 + tid];
    const float4 x1 = base[(size_t)s1 * 256 + tid];
    const float4 x2 = base[(size_t)s2 * 256 + tid];
    const float4 x3 = base[(size_t)s3 * 256 + tid];
    acc.x += w0*x0.x + w1*x1.x + w2*x2.x + w3*x3.x;
    acc.y += w0*x0.y + w1*x1.y + w2*x2.y + w3*x3.y;
    acc.z += w0*x0.z + w1*x1.z + w2*x2.z + w3*x3.z;
    acc.w += w0*x0.w + w1*x1.w + w2*x2.w + w3*x3.w;
  }
  float* o = out + b * II + tid * 4;
  atomicAdd(o + 0, acc.x);
  atomicAdd(o + 1, acc.y);
  atomicAdd(o + 2, acc.z);
  atomicAdd(o + 3, acc.w);
}

extern "C" void kernel_launch(void* const* d_in, const int* in_sizes, int n_in,
                              void* d_out, int out_size, void* d_ws, size_t ws_size,
                              hipStream_t stream) {
  const float* queries = (const float*)d_in[0];
  const float* items   = (const float*)d_in[1];
  const int*   weights = (const int*)d_in[2];
  const float* W       = (const float*)d_in[3];
  const float* U       = (const float*)d_in[4];
  const float* v       = (const float*)d_in[5];
  float* out = (float*)d_out;

  char* ws = (char*)d_ws;
  unsigned short* Ut = (unsigned short*)ws;                         // 2 MB
  float* pq    = (float*)(ws + (2u << 20));                         // 128 KB
  float* react = (float*)(ws + (2u << 20) + (128u << 10));          // 256 KB
  const size_t bf_off = (2u << 20) + (128u << 10) + (256u << 10);
  unsigned short* Aswz = (unsigned short*)(ws + bf_off);            // 128 MB (path A)
  const bool pathA = ws_size >= bf_off + (size_t)MM * II * 2;

  hipMemsetAsync(pq, 0, BB * AA * sizeof(float), stream);
  hipMemsetAsync(react, 0, MM * sizeof(float), stream);
  hipMemsetAsync(out, 0, BB * II * sizeof(float), stream);

  k_transpose_u<<<dim3(16, 16), 256, 0, stream>>>(U, Ut);
  k_pq<<<dim3(8, 4), 256, 0, stream>>>(queries, W, pq);
  if (pathA) {
    k_conv_swz<<<dim3(4096), 256, 0, stream>>>(items, Aswz);
    k_gemm_bf<<<dim3(4096), 256, 0, stream>>>(Aswz, Ut, pq, v, react);
  } else {
    k_gemm_f32<<<dim3(4096), 256, 0, stream>>>(items, Ut, pq, v, react);
  }
  k_softmax<<<dim3(BB), 256, 0, stream>>>(react, weights, out + BB * II);
  k_blended<<<dim3(BB, 16), 256, 0, stream>>>(items, out + BB * II, out);
}